// Round 18
// baseline (1886.908 us; speedup 1.0000x reference)
//
#include <hip/hip_runtime.h>
#include <hip/hip_bf16.h>
#include <hip/hip_cooperative_groups.h>

namespace cg = cooperative_groups;

#define NDIM 256
#define FDIM 32
#define HOPS 4

typedef __attribute__((ext_vector_type(8))) short short8;
typedef __attribute__((ext_vector_type(4))) float f32x4;
typedef __attribute__((ext_vector_type(2))) float f32x2;

// ---------- helpers ----------
__device__ inline float b2f(unsigned short u) {
    union { unsigned int i; float f; } v; v.i = ((unsigned int)u) << 16; return v.f;
}
__device__ inline unsigned short f2b(float f) {
    union { float f; unsigned int i; } v; v.f = f;
    unsigned int r = v.i + 0x7FFF + ((v.i >> 16) & 1);
    return (unsigned short)(r >> 16);
}
__device__ inline unsigned char f2fp8(float v) {
    return (unsigned char)(__builtin_amdgcn_cvt_pk_fp8_f32(v, v, 0, false) & 0xFF);
}

// ---------- CSR build ----------
__global__ void hist_kernel(const int* __restrict__ dst, int* __restrict__ deg, int E) {
    int e = blockIdx.x * blockDim.x + threadIdx.x;
    if (e < E) atomicAdd(&deg[dst[e]], 1);
}

__global__ __launch_bounds__(1024) void scan_kernel(const int* __restrict__ deg,
                                                    int* __restrict__ rowptr,
                                                    int* __restrict__ cursor, int n) {
    __shared__ int wsum[16];
    int t = threadIdx.x;
    int per4 = (n + 4095) >> 12;
    int base = t * per4 * 4;
    int4 v4[8];
#pragma unroll 8
    for (int j = 0; j < per4; ++j) {
        int4 d = *(const int4*)(deg + base + j * 4);
        d.x = (d.x + 7) & ~7; d.y = (d.y + 7) & ~7;
        d.z = (d.z + 7) & ~7; d.w = (d.w + 7) & ~7;
        v4[j] = d;
    }
    int s = 0;
#pragma unroll 8
    for (int j = 0; j < per4; ++j) s += v4[j].x + v4[j].y + v4[j].z + v4[j].w;

    int lane = t & 63, wid = t >> 6;
    int v = s;
#pragma unroll
    for (int d = 1; d < 64; d <<= 1) {
        int u = __shfl_up(v, d, 64);
        if (lane >= d) v += u;
    }
    if (lane == 63) wsum[wid] = v;
    __syncthreads();
    if (wid == 0) {
        int ws = (lane < 16) ? wsum[lane] : 0;
#pragma unroll
        for (int d = 1; d < 16; d <<= 1) {
            int u = __shfl_up(ws, d, 64);
            if (lane >= d) ws += u;
        }
        if (lane < 16) wsum[lane] = ws;
    }
    __syncthreads();
    int run = (wid > 0 ? wsum[wid - 1] : 0) + (v - s);
#pragma unroll 8
    for (int j = 0; j < per4; ++j) {
        int idx = base + j * 4;
        int4 o;
        o.x = run; run += v4[j].x;
        o.y = run; run += v4[j].y;
        o.z = run; run += v4[j].z;
        o.w = run; run += v4[j].w;
        if (idx + 3 < n) {
            *(int4*)(rowptr + idx) = o;
            *(int4*)(cursor + idx) = o;
        } else if (idx < n) {
            const int* op = (const int*)&o;
            for (int e = 0; e < 4 && idx + e < n; ++e) {
                rowptr[idx + e] = op[e];
                cursor[idx + e] = op[e];
            }
        }
    }
    if (t == 1023) rowptr[n] = run;
}

__global__ void fill_kernel(const int* __restrict__ src, const int* __restrict__ dst,
                            int* __restrict__ cursor, int* __restrict__ col, int E) {
    int e = blockIdx.x * blockDim.x + threadIdx.x;
    if (e < E) {
        int d = dst[e];
        int p = atomicAdd(&cursor[d], 1);
        col[p] = src[e];
    }
}

__global__ void pad_kernel(const int* __restrict__ rowptr, const int* __restrict__ deg,
                           int* __restrict__ col, int n) {
    int v = blockIdx.x * blockDim.x + threadIdx.x;
    if (v < n) {
        int s = rowptr[v] + deg[v];
        int e = rowptr[v + 1];
        for (int i = s; i < e; ++i) col[i] = n;
    }
}

// ---------- Wu1 transpose ----------
__global__ __launch_bounds__(256) void wtrans_u1_kernel(const float* __restrict__ Wu,
                                                        unsigned short* __restrict__ WtB) {
    int hop = blockIdx.z;
    const float* src = Wu + (size_t)hop * 512 * 256;
    unsigned short* dstp = WtB + (size_t)hop * 256 * 256;
    int k0 = blockIdx.x * 32, n0 = blockIdx.y * 32;
    __shared__ float T[32][33];
    int tr = threadIdx.x >> 5, tc = threadIdx.x & 31;
#pragma unroll
    for (int r = 0; r < 4; ++r) {
        int k = tr + r * 8;
        T[tc][k] = src[(size_t)(k0 + k) * 256 + n0 + tc];
    }
    __syncthreads();
#pragma unroll
    for (int r = 0; r < 4; ++r) {
        int nn = tr + r * 8;
        dstp[(size_t)(n0 + nn) * 256 + k0 + tc] = f2b(T[nn][tc]);
    }
}

// ---------- M1/M2 precompute ----------
__global__ __launch_bounds__(256) void mm_kernel(const float* __restrict__ Wm,
                                                 const float* __restrict__ Wu,
                                                 unsigned short* __restrict__ WtA,
                                                 unsigned short* __restrict__ WtC) {
    int m = blockIdx.z;
    int hop = m >> 1, which = m & 1;
    const float* A = Wm + (size_t)hop * 512 * 256 + (size_t)which * 256 * 256;
    const float* B = Wu + (size_t)hop * 512 * 256 + (size_t)256 * 256;
    unsigned short* W = (which ? WtC : WtA) + (size_t)hop * 256 * 256;
    int k0 = blockIdx.x * 64, n0 = blockIdx.y * 64;
    __shared__ float As[32][68];
    __shared__ float Bs[32][68];
    int t = threadIdx.x;
    int tx = t & 15, ty = t >> 4;
    float acc[4][4];
#pragma unroll
    for (int a = 0; a < 4; ++a)
#pragma unroll
        for (int b = 0; b < 4; ++b) acc[a][b] = 0.f;

    for (int j0 = 0; j0 < 256; j0 += 32) {
        __syncthreads();
#pragma unroll
        for (int c = 0; c < 2; ++c) {
            int idx = t + c * 256;
            int kk = idx >> 3;
            int jj = (idx & 7) * 4;
            float4 va = *(const float4*)&A[(size_t)(k0 + kk) * 256 + j0 + jj];
            As[jj + 0][kk] = va.x; As[jj + 1][kk] = va.y;
            As[jj + 2][kk] = va.z; As[jj + 3][kk] = va.w;
            int jj2 = idx >> 4;
            int nn = (idx & 15) * 4;
            float4 vb = *(const float4*)&B[(size_t)(j0 + jj2) * 256 + n0 + nn];
            *(float4*)&Bs[jj2][nn] = vb;
        }
        __syncthreads();
#pragma unroll
        for (int jj = 0; jj < 32; ++jj) {
            float av[4];
#pragma unroll
            for (int a = 0; a < 4; ++a) av[a] = As[jj][ty * 4 + a];
            float4 bv = *(const float4*)&Bs[jj][tx * 4];
#pragma unroll
            for (int a = 0; a < 4; ++a) {
                acc[a][0] += av[a] * bv.x; acc[a][1] += av[a] * bv.y;
                acc[a][2] += av[a] * bv.z; acc[a][3] += av[a] * bv.w;
            }
        }
    }
#pragma unroll
    for (int b = 0; b < 4; ++b) {
        int nn = n0 + tx * 4 + b;
        ushort4 o;
        o.x = f2b(acc[0][b]); o.y = f2b(acc[1][b]);
        o.z = f2b(acc[2][b]); o.w = f2b(acc[3][b]);
        *(ushort4*)&W[(size_t)nn * 256 + k0 + ty * 4] = o;
    }
}

// ---------- cvec ----------
__global__ __launch_bounds__(256) void cvec_kernel(const float* __restrict__ bm,
                                                   const float* __restrict__ Wu,
                                                   float* __restrict__ cvec) {
    int hop = blockIdx.x;
    int t = threadIdx.x;
    __shared__ float sb[256];
    sb[t] = bm[hop * 256 + t];
    __syncthreads();
    const float* B = Wu + (size_t)hop * 512 * 256 + (size_t)256 * 256;
    float acc = 0.f;
#pragma unroll 8
    for (int j = 0; j < 256; ++j) acc += sb[j] * B[(size_t)j * 256 + t];
    cvec[hop * 256 + t] = acc;
}

// ---------- initial projection (writes bf16 h + fp8 h8) ----------
__global__ void init_h_kernel(const float* __restrict__ nodes,
                              const int* __restrict__ node_types,
                              const float* __restrict__ type_emb,
                              const float* __restrict__ W_proj,
                              const float* __restrict__ b_proj,
                              unsigned short* __restrict__ h,
                              unsigned char* __restrict__ h8, int n) {
    int v = blockIdx.x;
    int t = threadIdx.x;
    __shared__ float sn[FDIM];
    if (t < FDIM) sn[t] = nodes[v * FDIM + t];
    __syncthreads();
    int ty = node_types[v];
    float acc = b_proj[t] + type_emb[ty * NDIM + t];
#pragma unroll
    for (int k = 0; k < FDIM; ++k) acc += sn[k] * W_proj[k * NDIM + t];
    h[(size_t)v * NDIM + t] = f2b(acc);
    h8[(size_t)v * NDIM + t] = f2fp8(acc);
}

#define BM 128
#define BN 64
#define BK 64
#define ASTR (BK + 8)

// ---------- device helpers shared by coop + fallback ----------
__device__ __forceinline__ void agg_rows_for(const unsigned char* __restrict__ h8,
                                             const int* __restrict__ rowptr,
                                             const int* __restrict__ col,
                                             unsigned short* __restrict__ Sb,
                                             int v, int cofs) {
    int beg = rowptr[v], end = rowptr[v + 1];
    float a[8];
#pragma unroll
    for (int e = 0; e < 8; ++e) a[e] = 0.f;
    for (int i = beg; i < end; i += 8) {
        int cc[8];
#pragma unroll
        for (int jj = 0; jj < 8; ++jj) cc[jj] = col[i + jj];
        uint2 x[8];
#pragma unroll
        for (int jj = 0; jj < 8; ++jj)
            x[jj] = *(const uint2*)(h8 + (size_t)cc[jj] * NDIM + cofs);
#pragma unroll
        for (int jj = 0; jj < 8; ++jj) {
            f32x2 p0 = __builtin_amdgcn_cvt_pk_f32_fp8(x[jj].x, false);
            f32x2 p1 = __builtin_amdgcn_cvt_pk_f32_fp8(x[jj].x, true);
            f32x2 p2 = __builtin_amdgcn_cvt_pk_f32_fp8(x[jj].y, false);
            f32x2 p3 = __builtin_amdgcn_cvt_pk_f32_fp8(x[jj].y, true);
            a[0] += p0[0]; a[1] += p0[1]; a[2] += p1[0]; a[3] += p1[1];
            a[4] += p2[0]; a[5] += p2[1]; a[6] += p3[0]; a[7] += p3[1];
        }
    }
    uint4 o;
    unsigned short* op = (unsigned short*)&o;
#pragma unroll
    for (int e = 0; e < 8; ++e) op[e] = f2b(a[e]);
    *(uint4*)&Sb[(size_t)v * NDIM + cofs] = o;
}

// gemm tile body; As/Bs/Cs/smax passed as LDS pointers
__device__ __forceinline__ void gemm_tile(const unsigned short* __restrict__ S,
                                          const unsigned short* __restrict__ h,
                                          const int* __restrict__ deg,
                                          const unsigned short* __restrict__ WtA,
                                          const unsigned short* __restrict__ WtB,
                                          const unsigned short* __restrict__ WtC,
                                          const float* __restrict__ bupd,
                                          const float* __restrict__ cvec,
                                          unsigned short* __restrict__ Out,
                                          unsigned char* __restrict__ Out8,
                                          int* __restrict__ geInt,
                                          unsigned short (*As)[ASTR],
                                          unsigned short (*Bs)[ASTR],
                                          unsigned short (*Cs)[ASTR],
                                          int* smax,
                                          int row0, int n0, bool last, int n) {
    int t = threadIdx.x;
    int lane = t & 63;
    int w = t >> 6;
    int wm = w >> 1, wn = w & 1;
    int quad = lane >> 4, l16 = lane & 15;

    if (last && t < BN) smax[t] = 0;

    f32x4 acc1[4][2], acc2[4][2];
#pragma unroll
    for (int i = 0; i < 4; ++i)
#pragma unroll
        for (int j = 0; j < 2; ++j) { acc1[i][j] = (f32x4)(0.f); acc2[i][j] = (f32x4)(0.f); }

    // phase 1: acc1 += S @ M1^T
    for (int k0 = 0; k0 < NDIM; k0 += BK) {
        __syncthreads();
#pragma unroll
        for (int h2 = 0; h2 < 4; ++h2) {
            int c = t + h2 * 256;
            int r = c >> 3;
            int ko = (c & 7) * 8;
            int grow = row0 + r; if (grow >= n) grow = n - 1;
            *(uint4*)&As[r][ko] = *(const uint4*)(S + (size_t)grow * NDIM + k0 + ko);
        }
#pragma unroll
        for (int h2 = 0; h2 < 2; ++h2) {
            int c = t + h2 * 256;
            int r = c >> 3;
            int ko = (c & 7) * 8;
            *(uint4*)&Bs[r][ko] = *(const uint4*)(WtA + (size_t)(n0 + r) * NDIM + k0 + ko);
        }
        __syncthreads();
#pragma unroll
        for (int ks = 0; ks < BK; ks += 32) {
            short8 af[4], bf[2];
#pragma unroll
            for (int mt = 0; mt < 4; ++mt)
                af[mt] = *(const short8*)&As[wm * 64 + mt * 16 + l16][ks + quad * 8];
#pragma unroll
            for (int nt = 0; nt < 2; ++nt)
                bf[nt] = *(const short8*)&Bs[wn * 32 + nt * 16 + l16][ks + quad * 8];
#pragma unroll
            for (int mt = 0; mt < 4; ++mt)
#pragma unroll
                for (int nt = 0; nt < 2; ++nt)
                    acc1[mt][nt] = __builtin_amdgcn_mfma_f32_16x16x32_bf16(af[mt], bf[nt], acc1[mt][nt], 0, 0, 0);
        }
    }
    // phase 2: acc1 += h @ Wu1^T ; acc2 += h @ M2^T
    for (int k0 = 0; k0 < NDIM; k0 += BK) {
        __syncthreads();
#pragma unroll
        for (int h2 = 0; h2 < 4; ++h2) {
            int c = t + h2 * 256;
            int r = c >> 3;
            int ko = (c & 7) * 8;
            int grow = row0 + r; if (grow >= n) grow = n - 1;
            *(uint4*)&As[r][ko] = *(const uint4*)(h + (size_t)grow * NDIM + k0 + ko);
        }
#pragma unroll
        for (int h2 = 0; h2 < 2; ++h2) {
            int c = t + h2 * 256;
            int r = c >> 3;
            int ko = (c & 7) * 8;
            size_t widx = (size_t)(n0 + r) * NDIM + k0 + ko;
            *(uint4*)&Bs[r][ko] = *(const uint4*)(WtB + widx);
            *(uint4*)&Cs[r][ko] = *(const uint4*)(WtC + widx);
        }
        __syncthreads();
#pragma unroll
        for (int ks = 0; ks < BK; ks += 32) {
            short8 af[4], bf[2], cf[2];
#pragma unroll
            for (int mt = 0; mt < 4; ++mt)
                af[mt] = *(const short8*)&As[wm * 64 + mt * 16 + l16][ks + quad * 8];
#pragma unroll
            for (int nt = 0; nt < 2; ++nt) {
                bf[nt] = *(const short8*)&Bs[wn * 32 + nt * 16 + l16][ks + quad * 8];
                cf[nt] = *(const short8*)&Cs[wn * 32 + nt * 16 + l16][ks + quad * 8];
            }
#pragma unroll
            for (int mt = 0; mt < 4; ++mt)
#pragma unroll
                for (int nt = 0; nt < 2; ++nt) {
                    acc1[mt][nt] = __builtin_amdgcn_mfma_f32_16x16x32_bf16(af[mt], bf[nt], acc1[mt][nt], 0, 0, 0);
                    acc2[mt][nt] = __builtin_amdgcn_mfma_f32_16x16x32_bf16(af[mt], cf[nt], acc2[mt][nt], 0, 0, 0);
                }
        }
    }
    // epilogue
#pragma unroll
    for (int mt = 0; mt < 4; ++mt) {
#pragma unroll
        for (int nt = 0; nt < 2; ++nt) {
            int lcol = wn * 32 + nt * 16 + l16;
            int colI = n0 + lcol;
            float bu = bupd[colI];
            float cv = cvec[colI];
            float cmax = 0.f;
#pragma unroll
            for (int r = 0; r < 4; ++r) {
                int row = row0 + wm * 64 + mt * 16 + quad * 4 + r;
                if (row < n) {
                    float dg = (float)deg[row];
                    float v = fmaxf(acc1[mt][nt][r] + dg * (acc2[mt][nt][r] + cv) + bu, 0.f);
                    Out[(size_t)row * NDIM + colI] = f2b(v);
                    if (!last) Out8[(size_t)row * NDIM + colI] = f2fp8(v);
                    else cmax = fmaxf(cmax, v);
                }
            }
            if (last) atomicMax(&smax[lcol], __float_as_int(cmax));
        }
    }
    if (last) {
        __syncthreads();
        if (t < BN) atomicMax(&geInt[n0 + t], smax[t]);
    }
}

// ---------- fallback standalone kernels (R15 structure) ----------
__global__ __launch_bounds__(256) void agg_kernel(const unsigned char* __restrict__ h8,
                                                  const int* __restrict__ rowptr,
                                                  const int* __restrict__ col,
                                                  unsigned short* __restrict__ S, int n) {
    int wave = threadIdx.x >> 6;
    int lane = threadIdx.x & 63;
    int half = lane >> 5;
    int hl = lane & 31;
    int v = blockIdx.x * 8 + wave * 2 + half;
    if (v >= n) return;
    agg_rows_for(h8, rowptr, col, S, v, hl * 8);
}

template <bool LAST>
__global__ __launch_bounds__(256) void gemm_hop_kernel(const unsigned short* __restrict__ S,
                                                       const unsigned short* __restrict__ hcur,
                                                       const int* __restrict__ deg,
                                                       const unsigned short* __restrict__ WtA,
                                                       const unsigned short* __restrict__ WtB,
                                                       const unsigned short* __restrict__ WtC,
                                                       const float* __restrict__ bupd,
                                                       const float* __restrict__ cvec,
                                                       unsigned short* __restrict__ Out,
                                                       unsigned char* __restrict__ Out8,
                                                       int* __restrict__ geInt, int n) {
    __shared__ unsigned short As[BM][ASTR];
    __shared__ unsigned short Bs[BN][ASTR];
    __shared__ unsigned short Cs[BN][ASTR];
    __shared__ int smax[BN];
    gemm_tile(S, hcur, deg, WtA, WtB, WtC, bupd, cvec, Out, Out8, geInt,
              As, Bs, Cs, smax, blockIdx.x * BM, blockIdx.y * BN, LAST, n);
}

// ---------- cooperative hop-loop mega kernel ----------
__global__ __launch_bounds__(256, 4) void gnn_loop_kernel(
        const int* __restrict__ rowptr, const int* __restrict__ col,
        const int* __restrict__ deg,
        const unsigned short* __restrict__ WtA_, const unsigned short* __restrict__ WtB_,
        const unsigned short* __restrict__ WtC_,
        const float* __restrict__ bupd_, const float* __restrict__ cvec_,
        unsigned short* hA, unsigned short* hB, unsigned short* Sb,
        unsigned char* h8, int* geInt, int n) {
    cg::grid_group gg = cg::this_grid();
    __shared__ unsigned short As[BM][ASTR];
    __shared__ unsigned short Bs[BN][ASTR];
    __shared__ unsigned short Cs[BN][ASTR];
    __shared__ int smax[BN];

    int t = threadIdx.x;
    int lane = t & 63;
    int w = t >> 6;
    unsigned short* h = hA;
    unsigned short* ho = hB;

    for (int hop = 0; hop < HOPS; ++hop) {
        bool last = (hop == HOPS - 1);
        // agg phase
        {
            int half = lane >> 5, hl = lane & 31;
            int unit = w * 2 + half;
            int cofs = hl * 8;
#pragma unroll
            for (int j = 0; j < 4; ++j) {
                int v = blockIdx.x * 32 + j * 8 + unit;
                if (v < n) agg_rows_for(h8, rowptr, col, Sb, v, cofs);
            }
        }
        __threadfence();
        gg.sync();
        // gemm phase
        {
            int bx = blockIdx.x >> 2, by = blockIdx.x & 3;
            gemm_tile(Sb, h, deg,
                      WtA_ + (size_t)hop * 256 * 256,
                      WtB_ + (size_t)hop * 256 * 256,
                      WtC_ + (size_t)hop * 256 * 256,
                      bupd_ + (size_t)hop * NDIM, cvec_ + (size_t)hop * NDIM,
                      ho, h8, geInt, As, Bs, Cs, smax,
                      bx * BM, by * BN, last, n);
        }
        __threadfence();
        gg.sync();
        unsigned short* tmp = h; h = ho; ho = tmp;
    }
}

// ---------- final ----------
__global__ __launch_bounds__(1024) void out_kernel(const float* __restrict__ ge,
                                                   const float* __restrict__ W_out,
                                                   const float* __restrict__ b_out,
                                                   float* __restrict__ out) {
    __shared__ float red[4][NDIM];
    int t = threadIdx.x & 255;
    int g = threadIdx.x >> 8;
    float acc = 0.f;
#pragma unroll 8
    for (int kk = 0; kk < 64; ++kk) {
        int k = g * 64 + kk;
        acc += ge[k] * W_out[k * NDIM + t];
    }
    red[g][t] = acc;
    __syncthreads();
    if (g == 0)
        out[t] = b_out[t] + red[0][t] + red[1][t] + red[2][t] + red[3][t];
}

// ---------- launch ----------
extern "C" void kernel_launch(void* const* d_in, const int* in_sizes, int n_in,
                              void* d_out, int out_size, void* d_ws, size_t ws_size,
                              hipStream_t stream) {
    const float* nodes      = (const float*)d_in[0];
    const int*   edges      = (const int*)d_in[1];
    const int*   node_types = (const int*)d_in[2];
    const float* type_emb   = (const float*)d_in[3];
    const float* W_proj     = (const float*)d_in[4];
    const float* b_proj     = (const float*)d_in[5];
    const float* W_msg      = (const float*)d_in[6];
    const float* b_msg      = (const float*)d_in[7];
    const float* W_upd      = (const float*)d_in[8];
    const float* b_upd      = (const float*)d_in[9];
    const float* W_out      = (const float*)d_in[10];
    const float* b_out      = (const float*)d_in[11];

    int n = in_sizes[2];
    int E = in_sizes[1] / 2;
    const int* src = edges;
    const int* dst = edges + E;

    size_t off = 0;
    auto alloc = [&](size_t bytes) {
        void* p = (char*)d_ws + off;
        off += (bytes + 255) & ~(size_t)255;
        return p;
    };
    int* deg    = (int*)alloc((size_t)(n + 4096) * 4);
    int* rowptr = (int*)alloc((size_t)(n + 1) * 4);
    int* cursor = (int*)alloc((size_t)n * 4);
    int* col    = (int*)alloc((size_t)(E + 8 * n) * 4);
    unsigned short* WtA = (unsigned short*)alloc((size_t)HOPS * 256 * 256 * 2);
    unsigned short* WtB = (unsigned short*)alloc((size_t)HOPS * 256 * 256 * 2);
    unsigned short* WtC = (unsigned short*)alloc((size_t)HOPS * 256 * 256 * 2);
    float* cvec = (float*)alloc((size_t)HOPS * 256 * 4);
    int* geInt  = (int*)alloc((size_t)256 * 4);
    unsigned short* hA  = (unsigned short*)alloc((size_t)(n + 1) * NDIM * 2);
    unsigned short* hB  = (unsigned short*)alloc((size_t)(n + 1) * NDIM * 2);
    unsigned short* Sb  = (unsigned short*)alloc((size_t)n * NDIM * 2);
    unsigned char* h8   = (unsigned char*)alloc((size_t)(n + 1) * NDIM);

    hipMemsetAsync(deg, 0, (size_t)(n + 4096) * 4, stream);
    hipMemsetAsync(geInt, 0, 256 * 4, stream);
    hipMemsetAsync(h8 + (size_t)n * NDIM, 0, NDIM, stream);
    int eb = (E + 255) / 256;
    hist_kernel<<<eb, 256, 0, stream>>>(dst, deg, E);
    scan_kernel<<<1, 1024, 0, stream>>>(deg, rowptr, cursor, n);
    fill_kernel<<<eb, 256, 0, stream>>>(src, dst, cursor, col, E);
    pad_kernel<<<(n + 255) / 256, 256, 0, stream>>>(rowptr, deg, col, n);
    wtrans_u1_kernel<<<dim3(8, 8, HOPS), 256, 0, stream>>>(W_upd, WtB);
    mm_kernel<<<dim3(4, 4, 2 * HOPS), 256, 0, stream>>>(W_msg, W_upd, WtA, WtC);
    cvec_kernel<<<HOPS, 256, 0, stream>>>(b_msg, W_upd, cvec);
    init_h_kernel<<<n, 256, 0, stream>>>(nodes, node_types, type_emb, W_proj, b_proj, hA, h8, n);

    int gx = (n + BM - 1) / BM;               // 196
    int nblocks = gx * (NDIM / BN);           // 784
    void* kargs[] = {
        (void*)&rowptr, (void*)&col, (void*)&deg,
        (void*)&WtA, (void*)&WtB, (void*)&WtC,
        (void*)&b_upd, (void*)&cvec,
        (void*)&hA, (void*)&hB, (void*)&Sb, (void*)&h8, (void*)&geInt, (void*)&n
    };
    hipError_t cerr = hipLaunchCooperativeKernel((void*)gnn_loop_kernel, dim3(nblocks),
                                                 dim3(256), kargs, 0, stream);
    if (cerr != hipSuccess) {
        (void)hipGetLastError();   // clear sticky error
        // fallback: per-hop launches (identical math, R15 structure)
        unsigned short* h  = hA;
        unsigned short* ho = hB;
        dim3 ggrid(gx, NDIM / BN);
        for (int i = 0; i < HOPS; ++i) {
            agg_kernel<<<(n + 7) / 8, 256, 0, stream>>>(h8, rowptr, col, Sb, n);
            size_t wofs = (size_t)i * 256 * 256;
            if (i == HOPS - 1)
                gemm_hop_kernel<true><<<ggrid, 256, 0, stream>>>(
                    Sb, h, deg, WtA + wofs, WtB + wofs, WtC + wofs,
                    b_upd + (size_t)i * NDIM, cvec + (size_t)i * NDIM, ho, h8, geInt, n);
            else
                gemm_hop_kernel<false><<<ggrid, 256, 0, stream>>>(
                    Sb, h, deg, WtA + wofs, WtB + wofs, WtC + wofs,
                    b_upd + (size_t)i * NDIM, cvec + (size_t)i * NDIM, ho, h8, geInt, n);
            unsigned short* tmp = h; h = ho; ho = tmp;
        }
    }

    out_kernel<<<1, 1024, 0, stream>>>((const float*)geInt, W_out, b_out, (float*)d_out);
}

// Round 19
// 441.309 us; speedup vs baseline: 4.2757x; 4.2757x over previous
//
#include <hip/hip_runtime.h>
#include <hip/hip_bf16.h>

#define NDIM 256
#define FDIM 32
#define HOPS 4

typedef __attribute__((ext_vector_type(8))) short short8;
typedef __attribute__((ext_vector_type(4))) float f32x4;
typedef __attribute__((ext_vector_type(2))) float f32x2;

// ---------- helpers ----------
__device__ inline float b2f(unsigned short u) {
    union { unsigned int i; float f; } v; v.i = ((unsigned int)u) << 16; return v.f;
}
__device__ inline unsigned short f2b(float f) {
    union { float f; unsigned int i; } v; v.f = f;
    unsigned int r = v.i + 0x7FFF + ((v.i >> 16) & 1);
    return (unsigned short)(r >> 16);
}
__device__ inline unsigned char f2fp8(float v) {
    return (unsigned char)(__builtin_amdgcn_cvt_pk_fp8_f32(v, v, 0, false) & 0xFF);
}

// ---------- CSR build ----------
__global__ void hist_kernel(const int* __restrict__ dst, int* __restrict__ deg, int E) {
    int e = blockIdx.x * blockDim.x + threadIdx.x;
    if (e < E) atomicAdd(&deg[dst[e]], 1);
}

// 1024-thread scan over degree-PADDED (mult of 8) counts; also writes col pad slots.
__global__ __launch_bounds__(1024) void scan_kernel(const int* __restrict__ deg,
                                                    int* __restrict__ rowptr,
                                                    int* __restrict__ cursor,
                                                    int* __restrict__ col, int n) {
    __shared__ int wsum[16];
    int t = threadIdx.x;
    int per4 = (n + 4095) >> 12;
    int base = t * per4 * 4;
    int4 d4[8], v4[8];
#pragma unroll 8
    for (int j = 0; j < per4; ++j) {
        int4 d = *(const int4*)(deg + base + j * 4);
        d4[j] = d;
        int4 p;
        p.x = (d.x + 7) & ~7; p.y = (d.y + 7) & ~7;
        p.z = (d.z + 7) & ~7; p.w = (d.w + 7) & ~7;
        v4[j] = p;
    }
    int s = 0;
#pragma unroll 8
    for (int j = 0; j < per4; ++j) s += v4[j].x + v4[j].y + v4[j].z + v4[j].w;

    int lane = t & 63, wid = t >> 6;
    int v = s;
#pragma unroll
    for (int d = 1; d < 64; d <<= 1) {
        int u = __shfl_up(v, d, 64);
        if (lane >= d) v += u;
    }
    if (lane == 63) wsum[wid] = v;
    __syncthreads();
    if (wid == 0) {
        int ws = (lane < 16) ? wsum[lane] : 0;
#pragma unroll
        for (int d = 1; d < 16; d <<= 1) {
            int u = __shfl_up(ws, d, 64);
            if (lane >= d) ws += u;
        }
        if (lane < 16) wsum[lane] = ws;
    }
    __syncthreads();
    int run = (wid > 0 ? wsum[wid - 1] : 0) + (v - s);
#pragma unroll 8
    for (int j = 0; j < per4; ++j) {
        int idx = base + j * 4;
        int4 o;
        o.x = run; run += v4[j].x;
        o.y = run; run += v4[j].y;
        o.z = run; run += v4[j].z;
        o.w = run; run += v4[j].w;
        if (idx + 3 < n) {
            *(int4*)(rowptr + idx) = o;
            *(int4*)(cursor + idx) = o;
        } else if (idx < n) {
            const int* op0 = (const int*)&o;
            for (int e = 0; e < 4 && idx + e < n; ++e) {
                rowptr[idx + e] = op0[e];
                cursor[idx + e] = op0[e];
            }
        }
        // pad slots: [o.e + deg, o.e + padded_deg) -> n
        const int* op = (const int*)&o;
        const int* dp = (const int*)&d4[j];
        const int* pp = (const int*)&v4[j];
#pragma unroll
        for (int e = 0; e < 4; ++e) {
            if (idx + e < n) {
                int s0 = op[e] + dp[e], e0 = op[e] + pp[e];
                for (int i = s0; i < e0; ++i) col[i] = n;
            }
        }
    }
    if (t == 1023) rowptr[n] = run;
}

__global__ void fill_kernel(const int* __restrict__ src, const int* __restrict__ dst,
                            int* __restrict__ cursor, int* __restrict__ col, int E) {
    int e = blockIdx.x * blockDim.x + threadIdx.x;
    if (e < E) {
        int d = dst[e];
        int p = atomicAdd(&cursor[d], 1);
        col[p] = src[e];
    }
}

// ---------- merged weight prep: wtrans (blocks 0..255) + mm (256..383) + cvec (384..387) + zero (388) ----------
__global__ __launch_bounds__(256) void wprep_kernel(const float* __restrict__ Wm,
                                                    const float* __restrict__ Wu,
                                                    const float* __restrict__ bm,
                                                    unsigned short* __restrict__ WtA,
                                                    unsigned short* __restrict__ WtB,
                                                    unsigned short* __restrict__ WtC,
                                                    float* __restrict__ cvec,
                                                    int* __restrict__ geInt,
                                                    unsigned char* __restrict__ h8row) {
    __shared__ float T[32][33];
    __shared__ float Af[32][68];
    __shared__ float Bf[32][68];
    __shared__ float sb[256];
    int b = blockIdx.x;
    int t = threadIdx.x;

    if (b < 256) {
        // ---- wtrans: WtB[hop][nn][k] = W_upd[hop][k][nn], k in 0..255 ----
        int hop = b >> 6;
        int rem = b & 63;
        int k0 = (rem & 7) * 32, n0 = (rem >> 3) * 32;
        const float* src = Wu + (size_t)hop * 512 * 256;
        unsigned short* dstp = WtB + (size_t)hop * 256 * 256;
        int tr = t >> 5, tc = t & 31;
#pragma unroll
        for (int r = 0; r < 4; ++r) {
            int k = tr + r * 8;
            T[tc][k] = src[(size_t)(k0 + k) * 256 + n0 + tc];
        }
        __syncthreads();
#pragma unroll
        for (int r = 0; r < 4; ++r) {
            int nn = tr + r * 8;
            dstp[(size_t)(n0 + nn) * 256 + k0 + tc] = f2b(T[nn][tc]);
        }
    } else if (b < 384) {
        // ---- mm: M = Wm_half @ Wu2, stored transposed [nn][k] ----
        int idx = b - 256;
        int m = idx >> 4;                 // 0..7 = hop*2 + which
        int rem = idx & 15;
        int k0 = (rem & 3) * 64, n0 = (rem >> 2) * 64;
        int hop = m >> 1, which = m & 1;
        const float* A = Wm + (size_t)hop * 512 * 256 + (size_t)which * 256 * 256;
        const float* B = Wu + (size_t)hop * 512 * 256 + (size_t)256 * 256;
        unsigned short* W = (which ? WtC : WtA) + (size_t)hop * 256 * 256;
        int tx = t & 15, ty = t >> 4;
        float acc[4][4];
#pragma unroll
        for (int a = 0; a < 4; ++a)
#pragma unroll
            for (int c = 0; c < 4; ++c) acc[a][c] = 0.f;

        for (int j0 = 0; j0 < 256; j0 += 32) {
            __syncthreads();
#pragma unroll
            for (int c = 0; c < 2; ++c) {
                int idx2 = t + c * 256;
                int kk = idx2 >> 3;
                int jj = (idx2 & 7) * 4;
                float4 va = *(const float4*)&A[(size_t)(k0 + kk) * 256 + j0 + jj];
                Af[jj + 0][kk] = va.x; Af[jj + 1][kk] = va.y;
                Af[jj + 2][kk] = va.z; Af[jj + 3][kk] = va.w;
                int jj2 = idx2 >> 4;
                int nn = (idx2 & 15) * 4;
                float4 vb = *(const float4*)&B[(size_t)(j0 + jj2) * 256 + n0 + nn];
                *(float4*)&Bf[jj2][nn] = vb;
            }
            __syncthreads();
#pragma unroll
            for (int jj = 0; jj < 32; ++jj) {
                float av[4];
#pragma unroll
                for (int a = 0; a < 4; ++a) av[a] = Af[jj][ty * 4 + a];
                float4 bv = *(const float4*)&Bf[jj][tx * 4];
#pragma unroll
                for (int a = 0; a < 4; ++a) {
                    acc[a][0] += av[a] * bv.x; acc[a][1] += av[a] * bv.y;
                    acc[a][2] += av[a] * bv.z; acc[a][3] += av[a] * bv.w;
                }
            }
        }
#pragma unroll
        for (int c = 0; c < 4; ++c) {
            int nn = n0 + tx * 4 + c;
            ushort4 o;
            o.x = f2b(acc[0][c]); o.y = f2b(acc[1][c]);
            o.z = f2b(acc[2][c]); o.w = f2b(acc[3][c]);
            *(ushort4*)&W[(size_t)nn * 256 + k0 + ty * 4] = o;
        }
    } else if (b < 388) {
        // ---- cvec[hop] = b_msg[hop] @ Wu2[hop] ----
        int hop = b - 384;
        sb[t] = bm[hop * 256 + t];
        __syncthreads();
        const float* B = Wu + (size_t)hop * 512 * 256 + (size_t)256 * 256;
        float acc = 0.f;
#pragma unroll 8
        for (int j = 0; j < 256; ++j) acc += sb[j] * B[(size_t)j * 256 + t];
        cvec[hop * 256 + t] = acc;
    } else {
        // ---- zero geInt + h8 pad row ----
        geInt[t] = 0;
        h8row[t] = 0;
    }
}

// ---------- initial projection (writes bf16 h + fp8 h8) ----------
__global__ void init_h_kernel(const float* __restrict__ nodes,
                              const int* __restrict__ node_types,
                              const float* __restrict__ type_emb,
                              const float* __restrict__ W_proj,
                              const float* __restrict__ b_proj,
                              unsigned short* __restrict__ h,
                              unsigned char* __restrict__ h8, int n) {
    int v = blockIdx.x;
    int t = threadIdx.x;
    __shared__ float sn[FDIM];
    if (t < FDIM) sn[t] = nodes[v * FDIM + t];
    __syncthreads();
    int ty = node_types[v];
    float acc = b_proj[t] + type_emb[ty * NDIM + t];
#pragma unroll
    for (int k = 0; k < FDIM; ++k) acc += sn[k] * W_proj[k * NDIM + t];
    h[(size_t)v * NDIM + t] = f2b(acc);
    h8[(size_t)v * NDIM + t] = f2fp8(acc);
}

// ---------- neighbor sum: fp8 gather (256B rows), fp32 accumulate, bf16 out ----------
__global__ __launch_bounds__(256) void agg_kernel(const unsigned char* __restrict__ h8,
                                                  const int* __restrict__ rowptr,
                                                  const int* __restrict__ col,
                                                  unsigned short* __restrict__ S, int n) {
    int wave = threadIdx.x >> 6;
    int lane = threadIdx.x & 63;
    int half = lane >> 5;
    int hl = lane & 31;
    int v = blockIdx.x * 8 + wave * 2 + half;
    if (v >= n) return;
    int beg = rowptr[v], end = rowptr[v + 1];
    float a[8];
#pragma unroll
    for (int e = 0; e < 8; ++e) a[e] = 0.f;
    int cofs = hl * 8;
    for (int i = beg; i < end; i += 8) {
        int cc[8];
#pragma unroll
        for (int j = 0; j < 8; ++j) cc[j] = col[i + j];
        uint2 x[8];
#pragma unroll
        for (int j = 0; j < 8; ++j)
            x[j] = *(const uint2*)(h8 + (size_t)cc[j] * NDIM + cofs);
#pragma unroll
        for (int j = 0; j < 8; ++j) {
            f32x2 p0 = __builtin_amdgcn_cvt_pk_f32_fp8(x[j].x, false);
            f32x2 p1 = __builtin_amdgcn_cvt_pk_f32_fp8(x[j].x, true);
            f32x2 p2 = __builtin_amdgcn_cvt_pk_f32_fp8(x[j].y, false);
            f32x2 p3 = __builtin_amdgcn_cvt_pk_f32_fp8(x[j].y, true);
            a[0] += p0[0]; a[1] += p0[1]; a[2] += p1[0]; a[3] += p1[1];
            a[4] += p2[0]; a[5] += p2[1]; a[6] += p3[0]; a[7] += p3[1];
        }
    }
    uint4 o;
    unsigned short* op = (unsigned short*)&o;
#pragma unroll
    for (int e = 0; e < 8; ++e) op[e] = f2b(a[e]);
    *(uint4*)&S[(size_t)v * NDIM + cofs] = o;
}

// ---------- fused hop GEMM: BM=128 BN=64 BK=64 two-phase dual-acc (R15 config) ----------
#define BM 128
#define BN 64
#define BK 64
#define ASTR (BK + 8)

template <bool LAST>
__global__ __launch_bounds__(256) void gemm_hop_kernel(const unsigned short* __restrict__ S,
                                                       const unsigned short* __restrict__ hcur,
                                                       const int* __restrict__ deg,
                                                       const unsigned short* __restrict__ WtA,
                                                       const unsigned short* __restrict__ WtB,
                                                       const unsigned short* __restrict__ WtC,
                                                       const float* __restrict__ bupd,
                                                       const float* __restrict__ cvec,
                                                       unsigned short* __restrict__ Out,
                                                       unsigned char* __restrict__ Out8,
                                                       int* __restrict__ geInt, int n) {
    __shared__ unsigned short As[BM][ASTR];
    __shared__ unsigned short Bs[BN][ASTR];
    __shared__ unsigned short Cs[BN][ASTR];
    __shared__ int smax[BN];
    int t = threadIdx.x;
    int lane = t & 63;
    int w = t >> 6;
    int wm = w >> 1, wn = w & 1;
    int quad = lane >> 4, l16 = lane & 15;
    int row0 = blockIdx.x * BM;
    int n0 = blockIdx.y * BN;

    if (LAST) {
        if (t < BN) smax[t] = 0;
    }

    f32x4 acc1[4][2], acc2[4][2];
#pragma unroll
    for (int i = 0; i < 4; ++i)
#pragma unroll
        for (int j = 0; j < 2; ++j) { acc1[i][j] = (f32x4)(0.f); acc2[i][j] = (f32x4)(0.f); }

    // phase 1: acc1 += S @ M1^T
    for (int k0 = 0; k0 < NDIM; k0 += BK) {
        __syncthreads();
#pragma unroll
        for (int h2 = 0; h2 < 4; ++h2) {
            int c = t + h2 * 256;
            int r = c >> 3;
            int ko = (c & 7) * 8;
            int grow = row0 + r; if (grow >= n) grow = n - 1;
            *(uint4*)&As[r][ko] = *(const uint4*)(S + (size_t)grow * NDIM + k0 + ko);
        }
#pragma unroll
        for (int h2 = 0; h2 < 2; ++h2) {
            int c = t + h2 * 256;
            int r = c >> 3;
            int ko = (c & 7) * 8;
            *(uint4*)&Bs[r][ko] = *(const uint4*)(WtA + (size_t)(n0 + r) * NDIM + k0 + ko);
        }
        __syncthreads();
#pragma unroll
        for (int ks = 0; ks < BK; ks += 32) {
            short8 af[4], bf[2];
#pragma unroll
            for (int mt = 0; mt < 4; ++mt)
                af[mt] = *(const short8*)&As[wm * 64 + mt * 16 + l16][ks + quad * 8];
#pragma unroll
            for (int nt = 0; nt < 2; ++nt)
                bf[nt] = *(const short8*)&Bs[wn * 32 + nt * 16 + l16][ks + quad * 8];
#pragma unroll
            for (int mt = 0; mt < 4; ++mt)
#pragma unroll
                for (int nt = 0; nt < 2; ++nt)
                    acc1[mt][nt] = __builtin_amdgcn_mfma_f32_16x16x32_bf16(af[mt], bf[nt], acc1[mt][nt], 0, 0, 0);
        }
    }
    // phase 2: acc1 += h @ Wu1^T ; acc2 += h @ M2^T
    for (int k0 = 0; k0 < NDIM; k0 += BK) {
        __syncthreads();
#pragma unroll
        for (int h2 = 0; h2 < 4; ++h2) {
            int c = t + h2 * 256;
            int r = c >> 3;
            int ko = (c & 7) * 8;
            int grow = row0 + r; if (grow >= n) grow = n - 1;
            *(uint4*)&As[r][ko] = *(const uint4*)(hcur + (size_t)grow * NDIM + k0 + ko);
        }
#pragma unroll
        for (int h2 = 0; h2 < 2; ++h2) {
            int c = t + h2 * 256;
            int r = c >> 3;
            int ko = (c & 7) * 8;
            size_t widx = (size_t)(n0 + r) * NDIM + k0 + ko;
            *(uint4*)&Bs[r][ko] = *(const uint4*)(WtB + widx);
            *(uint4*)&Cs[r][ko] = *(const uint4*)(WtC + widx);
        }
        __syncthreads();
#pragma unroll
        for (int ks = 0; ks < BK; ks += 32) {
            short8 af[4], bf[2], cf[2];
#pragma unroll
            for (int mt = 0; mt < 4; ++mt)
                af[mt] = *(const short8*)&As[wm * 64 + mt * 16 + l16][ks + quad * 8];
#pragma unroll
            for (int nt = 0; nt < 2; ++nt) {
                bf[nt] = *(const short8*)&Bs[wn * 32 + nt * 16 + l16][ks + quad * 8];
                cf[nt] = *(const short8*)&Cs[wn * 32 + nt * 16 + l16][ks + quad * 8];
            }
#pragma unroll
            for (int mt = 0; mt < 4; ++mt)
#pragma unroll
                for (int nt = 0; nt < 2; ++nt) {
                    acc1[mt][nt] = __builtin_amdgcn_mfma_f32_16x16x32_bf16(af[mt], bf[nt], acc1[mt][nt], 0, 0, 0);
                    acc2[mt][nt] = __builtin_amdgcn_mfma_f32_16x16x32_bf16(af[mt], cf[nt], acc2[mt][nt], 0, 0, 0);
                }
        }
    }
    // epilogue
#pragma unroll
    for (int mt = 0; mt < 4; ++mt) {
#pragma unroll
        for (int nt = 0; nt < 2; ++nt) {
            int lcol = wn * 32 + nt * 16 + l16;
            int col = n0 + lcol;
            float bu = bupd[col];
            float cv = cvec[col];
            float cmax = 0.f;
#pragma unroll
            for (int r = 0; r < 4; ++r) {
                int row = row0 + wm * 64 + mt * 16 + quad * 4 + r;
                if (row < n) {
                    float dg = (float)deg[row];
                    float v = fmaxf(acc1[mt][nt][r] + dg * (acc2[mt][nt][r] + cv) + bu, 0.f);
                    Out[(size_t)row * NDIM + col] = f2b(v);
                    if (!LAST) Out8[(size_t)row * NDIM + col] = f2fp8(v);
                    if (LAST) cmax = fmaxf(cmax, v);
                }
            }
            if (LAST) atomicMax(&smax[lcol], __float_as_int(cmax));
        }
    }
    if (LAST) {
        __syncthreads();
        if (t < BN) atomicMax(&geInt[n0 + t], smax[t]);
    }
}

// ---------- final ----------
__global__ __launch_bounds__(1024) void out_kernel(const float* __restrict__ ge,
                                                   const float* __restrict__ W_out,
                                                   const float* __restrict__ b_out,
                                                   float* __restrict__ out) {
    __shared__ float red[4][NDIM];
    int t = threadIdx.x & 255;
    int g = threadIdx.x >> 8;
    float acc = 0.f;
#pragma unroll 8
    for (int kk = 0; kk < 64; ++kk) {
        int k = g * 64 + kk;
        acc += ge[k] * W_out[k * NDIM + t];
    }
    red[g][t] = acc;
    __syncthreads();
    if (g == 0)
        out[t] = b_out[t] + red[0][t] + red[1][t] + red[2][t] + red[3][t];
}

// ---------- launch ----------
extern "C" void kernel_launch(void* const* d_in, const int* in_sizes, int n_in,
                              void* d_out, int out_size, void* d_ws, size_t ws_size,
                              hipStream_t stream) {
    const float* nodes      = (const float*)d_in[0];
    const int*   edges      = (const int*)d_in[1];
    const int*   node_types = (const int*)d_in[2];
    const float* type_emb   = (const float*)d_in[3];
    const float* W_proj     = (const float*)d_in[4];
    const float* b_proj     = (const float*)d_in[5];
    const float* W_msg      = (const float*)d_in[6];
    const float* b_msg      = (const float*)d_in[7];
    const float* W_upd      = (const float*)d_in[8];
    const float* b_upd      = (const float*)d_in[9];
    const float* W_out      = (const float*)d_in[10];
    const float* b_out      = (const float*)d_in[11];

    int n = in_sizes[2];
    int E = in_sizes[1] / 2;
    const int* src = edges;
    const int* dst = edges + E;

    size_t off = 0;
    auto alloc = [&](size_t bytes) {
        void* p = (char*)d_ws + off;
        off += (bytes + 255) & ~(size_t)255;
        return p;
    };
    int* deg    = (int*)alloc((size_t)(n + 4096) * 4);
    int* rowptr = (int*)alloc((size_t)(n + 1) * 4);
    int* cursor = (int*)alloc((size_t)n * 4);
    int* col    = (int*)alloc((size_t)(E + 8 * n) * 4);
    unsigned short* WtA = (unsigned short*)alloc((size_t)HOPS * 256 * 256 * 2);
    unsigned short* WtB = (unsigned short*)alloc((size_t)HOPS * 256 * 256 * 2);
    unsigned short* WtC = (unsigned short*)alloc((size_t)HOPS * 256 * 256 * 2);
    float* cvec = (float*)alloc((size_t)HOPS * 256 * 4);
    int* geInt  = (int*)alloc((size_t)256 * 4);
    unsigned short* hA  = (unsigned short*)alloc((size_t)(n + 1) * NDIM * 2);
    unsigned short* hB  = (unsigned short*)alloc((size_t)(n + 1) * NDIM * 2);
    unsigned short* Sb  = (unsigned short*)alloc((size_t)n * NDIM * 2);
    unsigned char* h8   = (unsigned char*)alloc((size_t)(n + 1) * NDIM);

    hipMemsetAsync(deg, 0, (size_t)(n + 4096) * 4, stream);
    int eb = (E + 255) / 256;
    hist_kernel<<<eb, 256, 0, stream>>>(dst, deg, E);
    scan_kernel<<<1, 1024, 0, stream>>>(deg, rowptr, cursor, col, n);
    fill_kernel<<<eb, 256, 0, stream>>>(src, dst, cursor, col, E);
    wprep_kernel<<<389, 256, 0, stream>>>(W_msg, W_upd, b_msg, WtA, WtB, WtC, cvec,
                                          geInt, h8 + (size_t)n * NDIM);
    init_h_kernel<<<n, 256, 0, stream>>>(nodes, node_types, type_emb, W_proj, b_proj, hA, h8, n);

    unsigned short* h  = hA;
    unsigned short* ho = hB;
    int gx = (n + BM - 1) / BM;
    dim3 ggrid(gx, NDIM / BN);
    for (int i = 0; i < HOPS; ++i) {
        agg_kernel<<<(n + 7) / 8, 256, 0, stream>>>(h8, rowptr, col, Sb, n);
        size_t wofs = (size_t)i * 256 * 256;
        if (i == HOPS - 1)
            gemm_hop_kernel<true><<<ggrid, 256, 0, stream>>>(
                Sb, h, deg, WtA + wofs, WtB + wofs, WtC + wofs,
                b_upd + (size_t)i * NDIM, cvec + (size_t)i * NDIM, ho, h8, geInt, n);
        else
            gemm_hop_kernel<false><<<ggrid, 256, 0, stream>>>(
                Sb, h, deg, WtA + wofs, WtB + wofs, WtC + wofs,
                b_upd + (size_t)i * NDIM, cvec + (size_t)i * NDIM, ho, h8, geInt, n);
        unsigned short* tmp = h; h = ho; ho = tmp;
    }
    out_kernel<<<1, 1024, 0, stream>>>((const float*)geInt, W_out, b_out, (float*)d_out);
}

// Round 20
// 393.929 us; speedup vs baseline: 4.7900x; 1.1203x over previous
//
#include <hip/hip_runtime.h>
#include <hip/hip_bf16.h>

#define NDIM 256
#define FDIM 32
#define HOPS 4

typedef __attribute__((ext_vector_type(8))) short short8;
typedef __attribute__((ext_vector_type(4))) float f32x4;
typedef __attribute__((ext_vector_type(2))) float f32x2;

// ---------- helpers ----------
__device__ inline float b2f(unsigned short u) {
    union { unsigned int i; float f; } v; v.i = ((unsigned int)u) << 16; return v.f;
}
__device__ inline unsigned short f2b(float f) {
    union { float f; unsigned int i; } v; v.f = f;
    unsigned int r = v.i + 0x7FFF + ((v.i >> 16) & 1);
    return (unsigned short)(r >> 16);
}
__device__ inline unsigned char f2fp8(float v) {
    return (unsigned char)(__builtin_amdgcn_cvt_pk_fp8_f32(v, v, 0, false) & 0xFF);
}

// ---------- CSR build ----------
__global__ void hist_kernel(const int* __restrict__ dst, int* __restrict__ deg, int E) {
    int e = blockIdx.x * blockDim.x + threadIdx.x;
    if (e < E) atomicAdd(&deg[dst[e]], 1);
}

// 1024-thread scan over degree-PADDED (multiple of 8) counts, int4-batched (R15 version).
__global__ __launch_bounds__(1024) void scan_kernel(const int* __restrict__ deg,
                                                    int* __restrict__ rowptr,
                                                    int* __restrict__ cursor, int n) {
    __shared__ int wsum[16];
    int t = threadIdx.x;
    int per4 = (n + 4095) >> 12;
    int base = t * per4 * 4;
    int4 v4[8];
#pragma unroll 8
    for (int j = 0; j < per4; ++j) {
        int4 d = *(const int4*)(deg + base + j * 4);
        d.x = (d.x + 7) & ~7; d.y = (d.y + 7) & ~7;
        d.z = (d.z + 7) & ~7; d.w = (d.w + 7) & ~7;
        v4[j] = d;
    }
    int s = 0;
#pragma unroll 8
    for (int j = 0; j < per4; ++j) s += v4[j].x + v4[j].y + v4[j].z + v4[j].w;

    int lane = t & 63, wid = t >> 6;
    int v = s;
#pragma unroll
    for (int d = 1; d < 64; d <<= 1) {
        int u = __shfl_up(v, d, 64);
        if (lane >= d) v += u;
    }
    if (lane == 63) wsum[wid] = v;
    __syncthreads();
    if (wid == 0) {
        int ws = (lane < 16) ? wsum[lane] : 0;
#pragma unroll
        for (int d = 1; d < 16; d <<= 1) {
            int u = __shfl_up(ws, d, 64);
            if (lane >= d) ws += u;
        }
        if (lane < 16) wsum[lane] = ws;
    }
    __syncthreads();
    int run = (wid > 0 ? wsum[wid - 1] : 0) + (v - s);
#pragma unroll 8
    for (int j = 0; j < per4; ++j) {
        int idx = base + j * 4;
        int4 o;
        o.x = run; run += v4[j].x;
        o.y = run; run += v4[j].y;
        o.z = run; run += v4[j].z;
        o.w = run; run += v4[j].w;
        if (idx + 3 < n) {
            *(int4*)(rowptr + idx) = o;
            *(int4*)(cursor + idx) = o;
        } else if (idx < n) {
            const int* op = (const int*)&o;
            for (int e = 0; e < 4 && idx + e < n; ++e) {
                rowptr[idx + e] = op[e];
                cursor[idx + e] = op[e];
            }
        }
    }
    if (t == 1023) rowptr[n] = run;
}

__global__ void fill_kernel(const int* __restrict__ src, const int* __restrict__ dst,
                            int* __restrict__ cursor, int* __restrict__ col, int E) {
    int e = blockIdx.x * blockDim.x + threadIdx.x;
    if (e < E) {
        int d = dst[e];
        int p = atomicAdd(&cursor[d], 1);
        col[p] = src[e];
    }
}

// fill pad slots [rowptr[v]+deg[v], rowptr[v+1]) with index n (zero row) — many-block version
__global__ void pad_kernel(const int* __restrict__ rowptr, const int* __restrict__ deg,
                           int* __restrict__ col, int n) {
    int v = blockIdx.x * blockDim.x + threadIdx.x;
    if (v < n) {
        int s = rowptr[v] + deg[v];
        int e = rowptr[v + 1];
        for (int i = s; i < e; ++i) col[i] = n;
    }
}

// ---------- merged weight prep: wtrans (blocks 0..255) + mm (256..383) + cvec (384..387) + zero (388) ----------
__global__ __launch_bounds__(256) void wprep_kernel(const float* __restrict__ Wm,
                                                    const float* __restrict__ Wu,
                                                    const float* __restrict__ bm,
                                                    unsigned short* __restrict__ WtA,
                                                    unsigned short* __restrict__ WtB,
                                                    unsigned short* __restrict__ WtC,
                                                    float* __restrict__ cvec,
                                                    int* __restrict__ geInt,
                                                    unsigned char* __restrict__ h8row) {
    __shared__ float T[32][33];
    __shared__ float Af[32][68];
    __shared__ float Bf[32][68];
    __shared__ float sb[256];
    int b = blockIdx.x;
    int t = threadIdx.x;

    if (b < 256) {
        int hop = b >> 6;
        int rem = b & 63;
        int k0 = (rem & 7) * 32, n0 = (rem >> 3) * 32;
        const float* src = Wu + (size_t)hop * 512 * 256;
        unsigned short* dstp = WtB + (size_t)hop * 256 * 256;
        int tr = t >> 5, tc = t & 31;
#pragma unroll
        for (int r = 0; r < 4; ++r) {
            int k = tr + r * 8;
            T[tc][k] = src[(size_t)(k0 + k) * 256 + n0 + tc];
        }
        __syncthreads();
#pragma unroll
        for (int r = 0; r < 4; ++r) {
            int nn = tr + r * 8;
            dstp[(size_t)(n0 + nn) * 256 + k0 + tc] = f2b(T[nn][tc]);
        }
    } else if (b < 384) {
        int idx = b - 256;
        int m = idx >> 4;
        int rem = idx & 15;
        int k0 = (rem & 3) * 64, n0 = (rem >> 2) * 64;
        int hop = m >> 1, which = m & 1;
        const float* A = Wm + (size_t)hop * 512 * 256 + (size_t)which * 256 * 256;
        const float* B = Wu + (size_t)hop * 512 * 256 + (size_t)256 * 256;
        unsigned short* W = (which ? WtC : WtA) + (size_t)hop * 256 * 256;
        int tx = t & 15, ty = t >> 4;
        float acc[4][4];
#pragma unroll
        for (int a = 0; a < 4; ++a)
#pragma unroll
            for (int c = 0; c < 4; ++c) acc[a][c] = 0.f;

        for (int j0 = 0; j0 < 256; j0 += 32) {
            __syncthreads();
#pragma unroll
            for (int c = 0; c < 2; ++c) {
                int idx2 = t + c * 256;
                int kk = idx2 >> 3;
                int jj = (idx2 & 7) * 4;
                float4 va = *(const float4*)&A[(size_t)(k0 + kk) * 256 + j0 + jj];
                Af[jj + 0][kk] = va.x; Af[jj + 1][kk] = va.y;
                Af[jj + 2][kk] = va.z; Af[jj + 3][kk] = va.w;
                int jj2 = idx2 >> 4;
                int nn = (idx2 & 15) * 4;
                float4 vb = *(const float4*)&B[(size_t)(j0 + jj2) * 256 + n0 + nn];
                *(float4*)&Bf[jj2][nn] = vb;
            }
            __syncthreads();
#pragma unroll
            for (int jj = 0; jj < 32; ++jj) {
                float av[4];
#pragma unroll
                for (int a = 0; a < 4; ++a) av[a] = Af[jj][ty * 4 + a];
                float4 bv = *(const float4*)&Bf[jj][tx * 4];
#pragma unroll
                for (int a = 0; a < 4; ++a) {
                    acc[a][0] += av[a] * bv.x; acc[a][1] += av[a] * bv.y;
                    acc[a][2] += av[a] * bv.z; acc[a][3] += av[a] * bv.w;
                }
            }
        }
#pragma unroll
        for (int c = 0; c < 4; ++c) {
            int nn = n0 + tx * 4 + c;
            ushort4 o;
            o.x = f2b(acc[0][c]); o.y = f2b(acc[1][c]);
            o.z = f2b(acc[2][c]); o.w = f2b(acc[3][c]);
            *(ushort4*)&W[(size_t)nn * 256 + k0 + ty * 4] = o;
        }
    } else if (b < 388) {
        int hop = b - 384;
        sb[t] = bm[hop * 256 + t];
        __syncthreads();
        const float* B = Wu + (size_t)hop * 512 * 256 + (size_t)256 * 256;
        float acc = 0.f;
#pragma unroll 8
        for (int j = 0; j < 256; ++j) acc += sb[j] * B[(size_t)j * 256 + t];
        cvec[hop * 256 + t] = acc;
    } else {
        geInt[t] = 0;
        h8row[t] = 0;
    }
}

// ---------- initial projection (writes bf16 h + fp8 h8) ----------
__global__ void init_h_kernel(const float* __restrict__ nodes,
                              const int* __restrict__ node_types,
                              const float* __restrict__ type_emb,
                              const float* __restrict__ W_proj,
                              const float* __restrict__ b_proj,
                              unsigned short* __restrict__ h,
                              unsigned char* __restrict__ h8, int n) {
    int v = blockIdx.x;
    int t = threadIdx.x;
    __shared__ float sn[FDIM];
    if (t < FDIM) sn[t] = nodes[v * FDIM + t];
    __syncthreads();
    int ty = node_types[v];
    float acc = b_proj[t] + type_emb[ty * NDIM + t];
#pragma unroll
    for (int k = 0; k < FDIM; ++k) acc += sn[k] * W_proj[k * NDIM + t];
    h[(size_t)v * NDIM + t] = f2b(acc);
    h8[(size_t)v * NDIM + t] = f2fp8(acc);
}

// ---------- neighbor sum: fp8 gather (256B rows), fp32 accumulate, bf16 out ----------
__global__ __launch_bounds__(256) void agg_kernel(const unsigned char* __restrict__ h8,
                                                  const int* __restrict__ rowptr,
                                                  const int* __restrict__ col,
                                                  unsigned short* __restrict__ S, int n) {
    int wave = threadIdx.x >> 6;
    int lane = threadIdx.x & 63;
    int half = lane >> 5;
    int hl = lane & 31;
    int v = blockIdx.x * 8 + wave * 2 + half;
    if (v >= n) return;
    int beg = rowptr[v], end = rowptr[v + 1];
    float a[8];
#pragma unroll
    for (int e = 0; e < 8; ++e) a[e] = 0.f;
    int cofs = hl * 8;
    for (int i = beg; i < end; i += 8) {
        int cc[8];
#pragma unroll
        for (int j = 0; j < 8; ++j) cc[j] = col[i + j];
        uint2 x[8];
#pragma unroll
        for (int j = 0; j < 8; ++j)
            x[j] = *(const uint2*)(h8 + (size_t)cc[j] * NDIM + cofs);
#pragma unroll
        for (int j = 0; j < 8; ++j) {
            f32x2 p0 = __builtin_amdgcn_cvt_pk_f32_fp8(x[j].x, false);
            f32x2 p1 = __builtin_amdgcn_cvt_pk_f32_fp8(x[j].x, true);
            f32x2 p2 = __builtin_amdgcn_cvt_pk_f32_fp8(x[j].y, false);
            f32x2 p3 = __builtin_amdgcn_cvt_pk_f32_fp8(x[j].y, true);
            a[0] += p0[0]; a[1] += p0[1]; a[2] += p1[0]; a[3] += p1[1];
            a[4] += p2[0]; a[5] += p2[1]; a[6] += p3[0]; a[7] += p3[1];
        }
    }
    uint4 o;
    unsigned short* op = (unsigned short*)&o;
#pragma unroll
    for (int e = 0; e < 8; ++e) op[e] = f2b(a[e]);
    *(uint4*)&S[(size_t)v * NDIM + cofs] = o;
}

// ---------- fused hop GEMM: BM=128 BN=64 BK=64 two-phase dual-acc (R15 config) ----------
#define BM 128
#define BN 64
#define BK 64
#define ASTR (BK + 8)

template <bool LAST>
__global__ __launch_bounds__(256) void gemm_hop_kernel(const unsigned short* __restrict__ S,
                                                       const unsigned short* __restrict__ hcur,
                                                       const int* __restrict__ deg,
                                                       const unsigned short* __restrict__ WtA,
                                                       const unsigned short* __restrict__ WtB,
                                                       const unsigned short* __restrict__ WtC,
                                                       const float* __restrict__ bupd,
                                                       const float* __restrict__ cvec,
                                                       unsigned short* __restrict__ Out,
                                                       unsigned char* __restrict__ Out8,
                                                       int* __restrict__ geInt, int n) {
    __shared__ unsigned short As[BM][ASTR];
    __shared__ unsigned short Bs[BN][ASTR];
    __shared__ unsigned short Cs[BN][ASTR];
    __shared__ int smax[BN];
    int t = threadIdx.x;
    int lane = t & 63;
    int w = t >> 6;
    int wm = w >> 1, wn = w & 1;
    int quad = lane >> 4, l16 = lane & 15;
    int row0 = blockIdx.x * BM;
    int n0 = blockIdx.y * BN;

    if (LAST) {
        if (t < BN) smax[t] = 0;
    }

    f32x4 acc1[4][2], acc2[4][2];
#pragma unroll
    for (int i = 0; i < 4; ++i)
#pragma unroll
        for (int j = 0; j < 2; ++j) { acc1[i][j] = (f32x4)(0.f); acc2[i][j] = (f32x4)(0.f); }

    // phase 1: acc1 += S @ M1^T
    for (int k0 = 0; k0 < NDIM; k0 += BK) {
        __syncthreads();
#pragma unroll
        for (int h2 = 0; h2 < 4; ++h2) {
            int c = t + h2 * 256;
            int r = c >> 3;
            int ko = (c & 7) * 8;
            int grow = row0 + r; if (grow >= n) grow = n - 1;
            *(uint4*)&As[r][ko] = *(const uint4*)(S + (size_t)grow * NDIM + k0 + ko);
        }
#pragma unroll
        for (int h2 = 0; h2 < 2; ++h2) {
            int c = t + h2 * 256;
            int r = c >> 3;
            int ko = (c & 7) * 8;
            *(uint4*)&Bs[r][ko] = *(const uint4*)(WtA + (size_t)(n0 + r) * NDIM + k0 + ko);
        }
        __syncthreads();
#pragma unroll
        for (int ks = 0; ks < BK; ks += 32) {
            short8 af[4], bf[2];
#pragma unroll
            for (int mt = 0; mt < 4; ++mt)
                af[mt] = *(const short8*)&As[wm * 64 + mt * 16 + l16][ks + quad * 8];
#pragma unroll
            for (int nt = 0; nt < 2; ++nt)
                bf[nt] = *(const short8*)&Bs[wn * 32 + nt * 16 + l16][ks + quad * 8];
#pragma unroll
            for (int mt = 0; mt < 4; ++mt)
#pragma unroll
                for (int nt = 0; nt < 2; ++nt)
                    acc1[mt][nt] = __builtin_amdgcn_mfma_f32_16x16x32_bf16(af[mt], bf[nt], acc1[mt][nt], 0, 0, 0);
        }
    }
    // phase 2: acc1 += h @ Wu1^T ; acc2 += h @ M2^T
    for (int k0 = 0; k0 < NDIM; k0 += BK) {
        __syncthreads();
#pragma unroll
        for (int h2 = 0; h2 < 4; ++h2) {
            int c = t + h2 * 256;
            int r = c >> 3;
            int ko = (c & 7) * 8;
            int grow = row0 + r; if (grow >= n) grow = n - 1;
            *(uint4*)&As[r][ko] = *(const uint4*)(hcur + (size_t)grow * NDIM + k0 + ko);
        }
#pragma unroll
        for (int h2 = 0; h2 < 2; ++h2) {
            int c = t + h2 * 256;
            int r = c >> 3;
            int ko = (c & 7) * 8;
            size_t widx = (size_t)(n0 + r) * NDIM + k0 + ko;
            *(uint4*)&Bs[r][ko] = *(const uint4*)(WtB + widx);
            *(uint4*)&Cs[r][ko] = *(const uint4*)(WtC + widx);
        }
        __syncthreads();
#pragma unroll
        for (int ks = 0; ks < BK; ks += 32) {
            short8 af[4], bf[2], cf[2];
#pragma unroll
            for (int mt = 0; mt < 4; ++mt)
                af[mt] = *(const short8*)&As[wm * 64 + mt * 16 + l16][ks + quad * 8];
#pragma unroll
            for (int nt = 0; nt < 2; ++nt) {
                bf[nt] = *(const short8*)&Bs[wn * 32 + nt * 16 + l16][ks + quad * 8];
                cf[nt] = *(const short8*)&Cs[wn * 32 + nt * 16 + l16][ks + quad * 8];
            }
#pragma unroll
            for (int mt = 0; mt < 4; ++mt)
#pragma unroll
                for (int nt = 0; nt < 2; ++nt) {
                    acc1[mt][nt] = __builtin_amdgcn_mfma_f32_16x16x32_bf16(af[mt], bf[nt], acc1[mt][nt], 0, 0, 0);
                    acc2[mt][nt] = __builtin_amdgcn_mfma_f32_16x16x32_bf16(af[mt], cf[nt], acc2[mt][nt], 0, 0, 0);
                }
        }
    }
    // epilogue
#pragma unroll
    for (int mt = 0; mt < 4; ++mt) {
#pragma unroll
        for (int nt = 0; nt < 2; ++nt) {
            int lcol = wn * 32 + nt * 16 + l16;
            int col = n0 + lcol;
            float bu = bupd[col];
            float cv = cvec[col];
            float cmax = 0.f;
#pragma unroll
            for (int r = 0; r < 4; ++r) {
                int row = row0 + wm * 64 + mt * 16 + quad * 4 + r;
                if (row < n) {
                    float dg = (float)deg[row];
                    float v = fmaxf(acc1[mt][nt][r] + dg * (acc2[mt][nt][r] + cv) + bu, 0.f);
                    Out[(size_t)row * NDIM + col] = f2b(v);
                    if (!LAST) Out8[(size_t)row * NDIM + col] = f2fp8(v);
                    if (LAST) cmax = fmaxf(cmax, v);
                }
            }
            if (LAST) atomicMax(&smax[lcol], __float_as_int(cmax));
        }
    }
    if (LAST) {
        __syncthreads();
        if (t < BN) atomicMax(&geInt[n0 + t], smax[t]);
    }
}

// ---------- final ----------
__global__ __launch_bounds__(1024) void out_kernel(const float* __restrict__ ge,
                                                   const float* __restrict__ W_out,
                                                   const float* __restrict__ b_out,
                                                   float* __restrict__ out) {
    __shared__ float red[4][NDIM];
    int t = threadIdx.x & 255;
    int g = threadIdx.x >> 8;
    float acc = 0.f;
#pragma unroll 8
    for (int kk = 0; kk < 64; ++kk) {
        int k = g * 64 + kk;
        acc += ge[k] * W_out[k * NDIM + t];
    }
    red[g][t] = acc;
    __syncthreads();
    if (g == 0)
        out[t] = b_out[t] + red[0][t] + red[1][t] + red[2][t] + red[3][t];
}

// ---------- launch ----------
extern "C" void kernel_launch(void* const* d_in, const int* in_sizes, int n_in,
                              void* d_out, int out_size, void* d_ws, size_t ws_size,
                              hipStream_t stream) {
    const float* nodes      = (const float*)d_in[0];
    const int*   edges      = (const int*)d_in[1];
    const int*   node_types = (const int*)d_in[2];
    const float* type_emb   = (const float*)d_in[3];
    const float* W_proj     = (const float*)d_in[4];
    const float* b_proj     = (const float*)d_in[5];
    const float* W_msg      = (const float*)d_in[6];
    const float* b_msg      = (const float*)d_in[7];
    const float* W_upd      = (const float*)d_in[8];
    const float* b_upd      = (const float*)d_in[9];
    const float* W_out      = (const float*)d_in[10];
    const float* b_out      = (const float*)d_in[11];

    int n = in_sizes[2];
    int E = in_sizes[1] / 2;
    const int* src = edges;
    const int* dst = edges + E;

    size_t off = 0;
    auto alloc = [&](size_t bytes) {
        void* p = (char*)d_ws + off;
        off += (bytes + 255) & ~(size_t)255;
        return p;
    };
    int* deg    = (int*)alloc((size_t)(n + 4096) * 4);
    int* rowptr = (int*)alloc((size_t)(n + 1) * 4);
    int* cursor = (int*)alloc((size_t)n * 4);
    int* col    = (int*)alloc((size_t)(E + 8 * n) * 4);
    unsigned short* WtA = (unsigned short*)alloc((size_t)HOPS * 256 * 256 * 2);
    unsigned short* WtB = (unsigned short*)alloc((size_t)HOPS * 256 * 256 * 2);
    unsigned short* WtC = (unsigned short*)alloc((size_t)HOPS * 256 * 256 * 2);
    float* cvec = (float*)alloc((size_t)HOPS * 256 * 4);
    int* geInt  = (int*)alloc((size_t)256 * 4);
    unsigned short* hA  = (unsigned short*)alloc((size_t)(n + 1) * NDIM * 2);
    unsigned short* hB  = (unsigned short*)alloc((size_t)(n + 1) * NDIM * 2);
    unsigned short* Sb  = (unsigned short*)alloc((size_t)n * NDIM * 2);
    unsigned char* h8   = (unsigned char*)alloc((size_t)(n + 1) * NDIM);

    hipMemsetAsync(deg, 0, (size_t)(n + 4096) * 4, stream);
    int eb = (E + 255) / 256;
    hist_kernel<<<eb, 256, 0, stream>>>(dst, deg, E);
    scan_kernel<<<1, 1024, 0, stream>>>(deg, rowptr, cursor, n);
    fill_kernel<<<eb, 256, 0, stream>>>(src, dst, cursor, col, E);
    pad_kernel<<<(n + 255) / 256, 256, 0, stream>>>(rowptr, deg, col, n);
    wprep_kernel<<<389, 256, 0, stream>>>(W_msg, W_upd, b_msg, WtA, WtB, WtC, cvec,
                                          geInt, h8 + (size_t)n * NDIM);
    init_h_kernel<<<n, 256, 0, stream>>>(nodes, node_types, type_emb, W_proj, b_proj, hA, h8, n);

    unsigned short* h  = hA;
    unsigned short* ho = hB;
    int gx = (n + BM - 1) / BM;
    dim3 ggrid(gx, NDIM / BN);
    for (int i = 0; i < HOPS; ++i) {
        agg_kernel<<<(n + 7) / 8, 256, 0, stream>>>(h8, rowptr, col, Sb, n);
        size_t wofs = (size_t)i * 256 * 256;
        if (i == HOPS - 1)
            gemm_hop_kernel<true><<<ggrid, 256, 0, stream>>>(
                Sb, h, deg, WtA + wofs, WtB + wofs, WtC + wofs,
                b_upd + (size_t)i * NDIM, cvec + (size_t)i * NDIM, ho, h8, geInt, n);
        else
            gemm_hop_kernel<false><<<ggrid, 256, 0, stream>>>(
                Sb, h, deg, WtA + wofs, WtB + wofs, WtC + wofs,
                b_upd + (size_t)i * NDIM, cvec + (size_t)i * NDIM, ho, h8, geInt, n);
        unsigned short* tmp = h; h = ho; ho = tmp;
    }
    out_kernel<<<1, 1024, 0, stream>>>((const float*)geInt, W_out, b_out, (float*)d_out);
}